// Round 4
// baseline (435.102 us; speedup 1.0000x reference)
//
#include <hip/hip_runtime.h>
#include <hip/hip_bf16.h>
#include <cstdint>
#include <cstddef>

#define HIDDEN 1024
#define BATCH 16
#define SEQ 2048
#define M_TOTAL (BATCH*SEQ)
#define NEG_INF -1000000000.0f

typedef unsigned short u16;
typedef __bf16 bf16x8 __attribute__((ext_vector_type(8)));
typedef unsigned short u16x8 __attribute__((ext_vector_type(8)));
typedef unsigned short u16x4 __attribute__((ext_vector_type(4)));
typedef float f32x4 __attribute__((ext_vector_type(4)));

typedef const __attribute__((address_space(1))) void* gas_ptr;
typedef __attribute__((address_space(3))) void* las_ptr;

__device__ __forceinline__ u16 f2bf(float f) {
    unsigned int x = __float_as_uint(f);
    unsigned int r = (x + 0x7fffu + ((x >> 16) & 1u)) >> 16;
    return (u16)r;
}

__device__ __forceinline__ float fast_tanh(float x) {
    float e = __expf(2.0f * x);
    return 1.0f - 2.0f / (e + 1.0f);
}

// ---------------------------------------------------------------------------
// prep_all: one launch for conv (keys->bf16), w2t (W2 transpose->bf16),
// qproj (q@W1, W1 read ONCE).
//   blocks [0, conv_blocks)              : conv, 4 float4/thread
//   blocks [conv_blocks, conv_blocks+256): w2t 64x64 tiles
//   blocks [.., +16)                     : qproj, one block per 64-n slice
// LDS: 64*65 floats (16.6 KiB) shared by w2t tile / qproj reduction.
// ---------------------------------------------------------------------------
__global__ __launch_bounds__(256) void prep_all_kernel(
    const float* __restrict__ keys, u16* __restrict__ keysb,
    const float* __restrict__ W2,   u16* __restrict__ W2T,
    const float* __restrict__ q,    const float* __restrict__ W1,
    float* __restrict__ qp, int conv_blocks)
{
    __shared__ float lds[64 * 65];
    int bid = blockIdx.x;
    const int tid = threadIdx.x;

    if (bid < conv_blocks) {
        const float4* in4 = (const float4*)keys;
        u16x4* out4 = (u16x4*)keysb;
        int base = bid * 1024 + tid;
        float4 f[4];
        #pragma unroll
        for (int i = 0; i < 4; ++i) f[i] = in4[base + i * 256];
        #pragma unroll
        for (int i = 0; i < 4; ++i) {
            u16x4 p;
            p[0] = f2bf(f[i].x); p[1] = f2bf(f[i].y);
            p[2] = f2bf(f[i].z); p[3] = f2bf(f[i].w);
            out4[base + i * 256] = p;
        }
        return;
    }
    bid -= conv_blocks;

    if (bid < 256) {
        // W2T[n][k] = bf16(W2[k][n])
        const int n0 = (bid & 15) * 64, k0 = (bid >> 4) * 64;
        const int c = tid & 63, rb = tid >> 6;
        #pragma unroll
        for (int i = 0; i < 16; ++i) {
            int r = rb + i * 4;
            lds[r * 65 + c] = W2[(size_t)(k0 + r) * HIDDEN + n0 + c];
        }
        __syncthreads();
        #pragma unroll
        for (int i = 0; i < 16; ++i) {
            int r = rb + i * 4;
            W2T[(size_t)(n0 + r) * HIDDEN + k0 + c] = f2bf(lds[c * 65 + r]);
        }
        return;
    }
    bid -= 256;   // 0..15: qproj for n in [bid*64, bid*64+64)

    const int w = tid >> 6, lane = tid & 63;
    const int n = bid * 64 + lane;
    float acc[16];
    #pragma unroll
    for (int b = 0; b < 16; ++b) acc[b] = 0.f;
    const int k0 = w * 256;
    for (int k = k0; k < k0 + 256; k += 8) {
        float w1v[8];
        #pragma unroll
        for (int u = 0; u < 8; ++u)
            w1v[u] = W1[(size_t)(k + u) * HIDDEN + n];
        #pragma unroll
        for (int u = 0; u < 8; ++u)
            #pragma unroll
            for (int b = 0; b < 16; ++b)
                acc[b] += q[b * HIDDEN + k + u] * w1v[u];
    }
    #pragma unroll
    for (int b = 0; b < 16; ++b)
        lds[(w * 16 + b) * 64 + lane] = acc[b];
    __syncthreads();
    if (w == 0) {
        #pragma unroll
        for (int b = 0; b < 16; ++b) {
            float s = lds[b * 64 + lane] + lds[(16 + b) * 64 + lane]
                    + lds[(32 + b) * 64 + lane] + lds[(48 + b) * 64 + lane];
            qp[b * HIDDEN + n] = s;
        }
    }
}

// ---------------------------------------------------------------------------
// scores v3: 1D grid, bid = nt*256 + mt -> bid%8 == mt%8, so all 8 n-tile
// blocks of one m-tile land on the SAME XCD (keys fetched once per XCD-L2).
// bf16 A/B staged via global_load_lds(16B), XOR-swizzled LDS. 128x128 tile,
// BK=64, mfma 16x16x32. part layout: [m][16] (slot-major inner).
// ---------------------------------------------------------------------------
#define BM 128
#define BN 128
#define BK 64

__global__ __launch_bounds__(256) void scores_v3_kernel(
    const u16*   __restrict__ keysb,
    const u16*   __restrict__ W2T,
    const float* __restrict__ qp,
    const float* __restrict__ v,
    float*       __restrict__ part)
{
    __shared__ __align__(16) u16 Alds[BM * BK];
    __shared__ __align__(16) u16 Blds[BN * BK];

    const int tid  = threadIdx.x;
    const int mt   = blockIdx.x & 255;
    const int nt   = blockIdx.x >> 8;       // 0..7
    const int m0   = mt * BM;
    const int n0   = nt * BN;
    const int wave = tid >> 6, lane = tid & 63;
    const int wr = wave >> 1, wc = wave & 1;
    const int quad = lane >> 4, c16 = lane & 15;

    const int sr = tid >> 3;                // staging row 0..31 (+32 per i)
    const int sc = tid & 7;                 // staging 16B chunk 0..7

    f32x4 acc[4][4];
    #pragma unroll
    for (int i = 0; i < 4; ++i)
        #pragma unroll
        for (int j = 0; j < 4; ++j)
            acc[i][j] = f32x4{0.f, 0.f, 0.f, 0.f};

    for (int kt = 0; kt < HIDDEN; kt += BK) {
        __syncthreads();
        #pragma unroll
        for (int i = 0; i < 4; ++i) {
            int r = sr + i * 32;
            int csw = sc ^ (r & 7);
            const u16* src = keysb + (size_t)(m0 + r) * HIDDEN + kt + csw * 8;
            las_ptr dst = (las_ptr)((char*)Alds + (i * 256 + wave * 64) * 16);
            __builtin_amdgcn_global_load_lds((gas_ptr)src, dst, 16, 0, 0);
        }
        #pragma unroll
        for (int i = 0; i < 4; ++i) {
            int r = sr + i * 32;
            int csw = sc ^ (r & 7);
            const u16* src = W2T + (size_t)(n0 + r) * HIDDEN + kt + csw * 8;
            las_ptr dst = (las_ptr)((char*)Blds + (i * 256 + wave * 64) * 16);
            __builtin_amdgcn_global_load_lds((gas_ptr)src, dst, 16, 0, 0);
        }
        __syncthreads();

        #pragma unroll
        for (int ks = 0; ks < BK; ks += 32) {
            const int ch = (ks >> 3) + quad;
            bf16x8 af[4], bfr[4];
            #pragma unroll
            for (int i = 0; i < 4; ++i) {
                int row = wr * 64 + i * 16 + c16;
                af[i] = __builtin_bit_cast(bf16x8,
                    *(const u16x8*)&Alds[row * BK + ((ch ^ (row & 7)) << 3)]);
            }
            #pragma unroll
            for (int j = 0; j < 4; ++j) {
                int row = wc * 64 + j * 16 + c16;
                bfr[j] = __builtin_bit_cast(bf16x8,
                    *(const u16x8*)&Blds[row * BK + ((ch ^ (row & 7)) << 3)]);
            }
            #pragma unroll
            for (int i = 0; i < 4; ++i)
                #pragma unroll
                for (int j = 0; j < 4; ++j)
                    acc[i][j] = __builtin_amdgcn_mfma_f32_16x16x32_bf16(
                        af[i], bfr[j], acc[i][j], 0, 0, 0);
        }
    }

    const int b = m0 >> 11;
    float qv[4], vv[4];
    #pragma unroll
    for (int j = 0; j < 4; ++j) {
        int n = n0 + wc * 64 + j * 16 + c16;
        qv[j] = qp[b * HIDDEN + n];
        vv[j] = v[n];
    }
    const int slot = nt * 2 + wc;
    #pragma unroll
    for (int i = 0; i < 4; ++i) {
        #pragma unroll
        for (int r = 0; r < 4; ++r) {
            float s = 0.f;
            #pragma unroll
            for (int j = 0; j < 4; ++j)
                s += fast_tanh(acc[i][j][r] + qv[j]) * vv[j];
            s += __shfl_xor(s, 1);
            s += __shfl_xor(s, 2);
            s += __shfl_xor(s, 4);
            s += __shfl_xor(s, 8);
            if (c16 == 0) {
                int m = m0 + wr * 64 + i * 16 + quad * 4 + r;
                part[(size_t)m * 16 + slot] = s;
            }
        }
    }
}

// ---------------------------------------------------------------------------
// scores v1 fallback (ws too small): inline fp32->bf16 staging, same grid
// swizzle + part layout as v3.
// ---------------------------------------------------------------------------
#define LDA 72

__global__ __launch_bounds__(256) void scores_v1_kernel(
    const float* __restrict__ keys,
    const u16*   __restrict__ W2T,
    const float* __restrict__ qp,
    const float* __restrict__ v,
    float*       __restrict__ part)
{
    __shared__ __align__(16) u16 Alds[BM][LDA];
    __shared__ __align__(16) u16 Blds[BN][LDA];

    const int tid  = threadIdx.x;
    const int mt   = blockIdx.x & 255;
    const int nt   = blockIdx.x >> 8;
    const int m0   = mt * BM;
    const int n0   = nt * BN;
    const int wave = tid >> 6, lane = tid & 63;
    const int wr = wave >> 1, wc = wave & 1;
    const int quad = lane >> 4, c16 = lane & 15;

    f32x4 acc[4][4];
    #pragma unroll
    for (int i = 0; i < 4; ++i)
        #pragma unroll
        for (int j = 0; j < 4; ++j)
            acc[i][j] = f32x4{0.f, 0.f, 0.f, 0.f};

    for (int kt = 0; kt < HIDDEN; kt += BK) {
        __syncthreads();
        const float* gA = keys + (size_t)m0 * HIDDEN + kt;
        #pragma unroll
        for (int i = 0; i < 8; ++i) {
            int idx = tid + i * 256;
            int r = idx >> 4, c4 = idx & 15;
            float4 f = *(const float4*)(gA + (size_t)r * HIDDEN + c4 * 4);
            u16x4 pk;
            pk[0] = f2bf(f.x); pk[1] = f2bf(f.y);
            pk[2] = f2bf(f.z); pk[3] = f2bf(f.w);
            *(u16x4*)&Alds[r][c4 * 4] = pk;
        }
        #pragma unroll
        for (int i = 0; i < 4; ++i) {
            int idx = tid + i * 256;
            int r = idx >> 3, c8 = idx & 7;
            uint4 raw = ((const uint4*)(W2T + (size_t)(n0 + r) * HIDDEN + kt))[c8];
            *(uint4*)&Blds[r][c8 * 8] = raw;
        }
        __syncthreads();

        #pragma unroll
        for (int ks = 0; ks < BK; ks += 32) {
            bf16x8 af[4], bfr[4];
            #pragma unroll
            for (int i = 0; i < 4; ++i)
                af[i] = __builtin_bit_cast(bf16x8,
                    *(const u16x8*)&Alds[wr * 64 + i * 16 + c16][ks + quad * 8]);
            #pragma unroll
            for (int j = 0; j < 4; ++j)
                bfr[j] = __builtin_bit_cast(bf16x8,
                    *(const u16x8*)&Blds[wc * 64 + j * 16 + c16][ks + quad * 8]);
            #pragma unroll
            for (int i = 0; i < 4; ++i)
                #pragma unroll
                for (int j = 0; j < 4; ++j)
                    acc[i][j] = __builtin_amdgcn_mfma_f32_16x16x32_bf16(
                        af[i], bfr[j], acc[i][j], 0, 0, 0);
        }
    }

    const int b = m0 >> 11;
    float qv[4], vv[4];
    #pragma unroll
    for (int j = 0; j < 4; ++j) {
        int n = n0 + wc * 64 + j * 16 + c16;
        qv[j] = qp[b * HIDDEN + n];
        vv[j] = v[n];
    }
    const int slot = nt * 2 + wc;
    #pragma unroll
    for (int i = 0; i < 4; ++i) {
        #pragma unroll
        for (int r = 0; r < 4; ++r) {
            float s = 0.f;
            #pragma unroll
            for (int j = 0; j < 4; ++j)
                s += fast_tanh(acc[i][j][r] + qv[j]) * vv[j];
            s += __shfl_xor(s, 1);
            s += __shfl_xor(s, 2);
            s += __shfl_xor(s, 4);
            s += __shfl_xor(s, 8);
            if (c16 == 0) {
                int m = m0 + wr * 64 + i * 16 + quad * 4 + r;
                part[(size_t)m * 16 + slot] = s;
            }
        }
    }
}

// ---------------------------------------------------------------------------
// softmax: sum 16 part slots (now contiguous per m) -> mask -> softmax.
// ---------------------------------------------------------------------------
__global__ __launch_bounds__(1024) void softmax_kernel(
    const float* __restrict__ part, const int* __restrict__ mask,
    float* __restrict__ attn)
{
    const int b = blockIdx.x, tid = threadIdx.x;
    const int wave = tid >> 6, lane = tid & 63;
    __shared__ float red[16];
    float sc[2];
    float mx = -1e30f;
    #pragma unroll
    for (int j = 0; j < 2; ++j) {
        int s = tid + j * 1024;
        const float4* p4 = (const float4*)(part + ((size_t)(b * SEQ + s) << 4));
        float4 a0 = p4[0], a1 = p4[1], a2 = p4[2], a3 = p4[3];
        float a = (a0.x + a0.y + a0.z + a0.w) + (a1.x + a1.y + a1.z + a1.w)
                + (a2.x + a2.y + a2.z + a2.w) + (a3.x + a3.y + a3.z + a3.w);
        if (mask[b * SEQ + s] == 0) a = NEG_INF;
        sc[j] = a;
        mx = fmaxf(mx, a);
    }
    #pragma unroll
    for (int o = 32; o > 0; o >>= 1) mx = fmaxf(mx, __shfl_xor(mx, o));
    if (lane == 0) red[wave] = mx;
    __syncthreads();
    #pragma unroll
    for (int w = 0; w < 16; ++w) mx = fmaxf(mx, red[w]);
    float sum = 0.f;
    #pragma unroll
    for (int j = 0; j < 2; ++j) { sc[j] = __expf(sc[j] - mx); sum += sc[j]; }
    #pragma unroll
    for (int o = 32; o > 0; o >>= 1) sum += __shfl_xor(sum, o);
    __syncthreads();
    if (lane == 0) red[wave] = sum;
    __syncthreads();
    sum = 0.f;
    #pragma unroll
    for (int w = 0; w < 16; ++w) sum += red[w];
    float inv = 1.0f / sum;
    #pragma unroll
    for (int j = 0; j < 2; ++j)
        attn[b * SEQ + tid + j * 1024] = sc[j] * inv;
}

// ---------------------------------------------------------------------------
// context stage 1: ctxp[b*64+sch][h] = sum_{s in 32-chunk} attn*values
// ---------------------------------------------------------------------------
__global__ __launch_bounds__(256) void ctx_part_kernel(
    const float* __restrict__ values, const float* __restrict__ attn,
    float* __restrict__ ctxp)
{
    const int b = blockIdx.x, sch = blockIdx.y, tid = threadIdx.x;
    __shared__ float w[32];
    if (tid < 32) w[tid] = attn[b * SEQ + sch * 32 + tid];
    __syncthreads();
    float4 acc = {0.f, 0.f, 0.f, 0.f};
    const float4* V = (const float4*)(values
        + (size_t)b * SEQ * HIDDEN + (size_t)sch * 32 * HIDDEN);
    #pragma unroll 4
    for (int s = 0; s < 32; ++s) {
        float wv = w[s];
        if (wv != 0.0f) {
            float4 x = V[(size_t)s * (HIDDEN / 4) + tid];
            acc.x += wv * x.x; acc.y += wv * x.y;
            acc.z += wv * x.z; acc.w += wv * x.w;
        }
    }
    ((float4*)(ctxp + (size_t)(b * 64 + sch) * HIDDEN))[tid] = acc;
}

// context stage 2
__global__ __launch_bounds__(256) void ctx_reduce_kernel(
    const float* __restrict__ ctxp, float* __restrict__ ctx)
{
    const int b = blockIdx.x, tid = threadIdx.x;
    float4 acc = {0.f, 0.f, 0.f, 0.f};
    const float4* P = (const float4*)(ctxp + (size_t)b * 64 * HIDDEN);
    #pragma unroll 8
    for (int s = 0; s < 64; ++s) {
        float4 x = P[(size_t)s * (HIDDEN / 4) + tid];
        acc.x += x.x; acc.y += x.y; acc.z += x.z; acc.w += x.w;
    }
    ((float4*)(ctx + (size_t)b * HIDDEN))[tid] = acc;
}

// ---------------------------------------------------------------------------
extern "C" void kernel_launch(void* const* d_in, const int* in_sizes, int n_in,
                              void* d_out, int out_size, void* d_ws, size_t ws_size,
                              hipStream_t stream)
{
    const float* query  = (const float*)d_in[0];
    const float* keys   = (const float*)d_in[1];
    const float* values = (const float*)d_in[2];
    const int*   mask   = (const int*)d_in[3];
    const float* W1     = (const float*)d_in[4];
    const float* W2     = (const float*)d_in[5];
    const float* v      = (const float*)d_in[6];
    float* out = (float*)d_out;

    // ws layout: qp 64K | W2T 2M | part 2M | ctxp 4M | keysb 64M
    char* ws = (char*)d_ws;
    float* qp     = (float*)ws;
    u16*   w2t    = (u16*)(ws + (64 << 10));
    float* part   = (float*)(ws + (64 << 10) + (2 << 20));
    float* ctxp   = (float*)(ws + (64 << 10) + (4 << 20));
    u16*   keysb  = (u16*)(ws + (64 << 10) + (8 << 20));
    const size_t WS_BIG = (64 << 10) + (8 << 20) + ((size_t)64 << 20);

    float* attn_out = out + BATCH * HIDDEN;

    if (ws_size >= WS_BIG) {
        prep_all_kernel<<<8192 + 256 + 16, 256, 0, stream>>>(
            keys, keysb, W2, w2t, query, W1, qp, 8192);
        scores_v3_kernel<<<2048, 256, 0, stream>>>(keysb, w2t, qp, v, part);
        softmax_kernel<<<16, 1024, 0, stream>>>(part, mask, attn_out);
        ctx_part_kernel<<<dim3(16, 64), 256, 0, stream>>>(
            values, attn_out, ctxp);
        ctx_reduce_kernel<<<16, 256, 0, stream>>>(ctxp, out);
    } else {
        prep_all_kernel<<<256 + 16, 256, 0, stream>>>(
            keys, keysb, W2, w2t, query, W1, qp, 0);
        scores_v1_kernel<<<2048, 256, 0, stream>>>(keys, w2t, qp, v, part);
        softmax_kernel<<<16, 1024, 0, stream>>>(part, mask, attn_out);
        if (ws_size >= (64 << 10) + (8 << 20)) {
            ctx_part_kernel<<<dim3(16, 64), 256, 0, stream>>>(
                values, attn_out, ctxp);
            ctx_reduce_kernel<<<16, 256, 0, stream>>>(ctxp, out);
        } else {
            hipMemsetAsync(d_out, 0, BATCH * HIDDEN * sizeof(float), stream);
            ctx_part_kernel<<<dim3(16, 64), 256, 0, stream>>>(
                values, attn_out, (float*)d_ws);
            ctx_reduce_kernel<<<16, 256, 0, stream>>>((float*)d_ws, out);
        }
    }
}